// Round 2
// baseline (840.368 us; speedup 1.0000x reference)
//
#include <hip/hip_runtime.h>
#include <hip/hip_fp16.h>

#define NP 200000
#define NA 100000
#define NE 1200000

// ---------------- CSR build ----------------

__global__ __launch_bounds__(256) void hist_k(const int* __restrict__ row, int* __restrict__ cnt, int n) {
    int i = blockIdx.x * blockDim.x + threadIdx.x;
    int stride = gridDim.x * blockDim.x;
    for (; i < n; i += stride) atomicAdd(&cnt[row[i]], 1);
}

// exclusive scan, 1024 elements/block (256 thr x 4), partial per block + block sums
__global__ __launch_bounds__(256) void scan1_k(const int* __restrict__ in, int* __restrict__ out,
                                               int* __restrict__ bsums, int n) {
    __shared__ int lds[256];
    int t = threadIdx.x;
    int base = blockIdx.x * 1024 + t * 4;
    int v0 = (base + 0 < n) ? in[base + 0] : 0;
    int v1 = (base + 1 < n) ? in[base + 1] : 0;
    int v2 = (base + 2 < n) ? in[base + 2] : 0;
    int v3 = (base + 3 < n) ? in[base + 3] : 0;
    lds[t] = v0 + v1 + v2 + v3;
    __syncthreads();
    for (int off = 1; off < 256; off <<= 1) {
        int x = (t >= off) ? lds[t - off] : 0;
        __syncthreads();
        lds[t] += x;
        __syncthreads();
    }
    if (t == 255) bsums[blockIdx.x] = lds[255];
    int run = (t == 0) ? 0 : lds[t - 1];
    if (base + 0 < n) out[base + 0] = run; run += v0;
    if (base + 1 < n) out[base + 1] = run; run += v1;
    if (base + 2 < n) out[base + 2] = run; run += v2;
    if (base + 3 < n) out[base + 3] = run;
}

__global__ void scan2_k(int* bsums, int nb) {  // nb <= 256, single block
    __shared__ int lds[256];
    int t = threadIdx.x;
    int v = (t < nb) ? bsums[t] : 0;
    lds[t] = v;
    __syncthreads();
    for (int off = 1; off < 256; off <<= 1) {
        int x = (t >= off) ? lds[t - off] : 0;
        __syncthreads();
        lds[t] += x;
        __syncthreads();
    }
    if (t < nb) bsums[t] = (t == 0) ? 0 : lds[t - 1];
}

__global__ __launch_bounds__(256) void scan3_k(int* __restrict__ out, const int* __restrict__ bsums, int n) {
    int add = bsums[blockIdx.x];
    int base = blockIdx.x * 1024 + threadIdx.x * 4;
#pragma unroll
    for (int j = 0; j < 4; j++)
        if (base + j < n) out[base + j] += add;
}

__global__ __launch_bounds__(256) void scatter_k(const int* __restrict__ row, const int* __restrict__ col,
                                                 const float* __restrict__ val, const int* __restrict__ off,
                                                 int* __restrict__ cursor, int2* __restrict__ csr, int n) {
    int i = blockIdx.x * blockDim.x + threadIdx.x;
    int stride = gridDim.x * blockDim.x;
    for (; i < n; i += stride) {
        int r = row[i];
        int pos = off[r] + atomicAdd(&cursor[r], 1);
        csr[pos] = make_int2(col[i], __float_as_int(val[i]));
    }
}

// ---------------- SpMM gather, fp16 z-table ----------------
// 8 lanes per output row; each lane covers 8 dims (uint4 = 8 halves = 16B,
// 8 lanes x 16B = 128B coalesced per gathered z-row). fp32 accumulate.

__device__ __forceinline__ void fma_h8(float acc[8], float v, uint4 r) {
    __half2 h0 = *(__half2*)&r.x;
    __half2 h1 = *(__half2*)&r.y;
    __half2 h2 = *(__half2*)&r.z;
    __half2 h3 = *(__half2*)&r.w;
    float2 f0 = __half22float2(h0);
    float2 f1 = __half22float2(h1);
    float2 f2 = __half22float2(h2);
    float2 f3 = __half22float2(h3);
    acc[0] = fmaf(v, f0.x, acc[0]);
    acc[1] = fmaf(v, f0.y, acc[1]);
    acc[2] = fmaf(v, f1.x, acc[2]);
    acc[3] = fmaf(v, f1.y, acc[3]);
    acc[4] = fmaf(v, f2.x, acc[4]);
    acc[5] = fmaf(v, f2.y, acc[5]);
    acc[6] = fmaf(v, f3.x, acc[6]);
    acc[7] = fmaf(v, f3.y, acc[7]);
}

__device__ __forceinline__ void store_h8(uint4* out16, int g, int l, const float acc[8]) {
    __half2 p0 = __floats2half2_rn(acc[0], acc[1]);
    __half2 p1 = __floats2half2_rn(acc[2], acc[3]);
    __half2 p2 = __floats2half2_rn(acc[4], acc[5]);
    __half2 p3 = __floats2half2_rn(acc[6], acc[7]);
    uint4 o;
    o.x = *(unsigned*)&p0;
    o.y = *(unsigned*)&p1;
    o.z = *(unsigned*)&p2;
    o.w = *(unsigned*)&p3;
    out16[(size_t)g * 8 + l] = o;
}

__device__ __forceinline__ void store_f8(float4* out32, int g, int l, const float acc[8]) {
    out32[(size_t)g * 16 + l * 2 + 0] = make_float4(acc[0], acc[1], acc[2], acc[3]);
    out32[(size_t)g * 16 + l * 2 + 1] = make_float4(acc[4], acc[5], acc[6], acc[7]);
}

__global__ __launch_bounds__(256) void spmm_k(const int2* __restrict__ csr, const int* __restrict__ off,
                                              const int* __restrict__ cnt, const uint4* __restrict__ z,
                                              float4* __restrict__ out32, uint4* __restrict__ out16,
                                              int nrows) {
    int g = blockIdx.x * 32 + (threadIdx.x >> 3);
    int l = threadIdx.x & 7;
    if (g >= nrows) return;
    int start = off[g], deg = cnt[g];
    float acc[8];
#pragma unroll
    for (int i = 0; i < 8; i++) acc[i] = 0.f;
    for (int j = 0; j < deg; j += 4) {
        int j1 = min(j + 1, deg - 1);
        int j2 = min(j + 2, deg - 1);
        int j3 = min(j + 3, deg - 1);
        int2 e0 = csr[start + j];
        int2 e1 = csr[start + j1];
        int2 e2 = csr[start + j2];
        int2 e3 = csr[start + j3];
        uint4 r0 = z[e0.x * 8 + l];
        uint4 r1 = z[e1.x * 8 + l];
        uint4 r2 = z[e2.x * 8 + l];
        uint4 r3 = z[e3.x * 8 + l];
        float v0 = __int_as_float(e0.y);
        float v1 = (j + 1 < deg) ? __int_as_float(e1.y) : 0.f;
        float v2 = (j + 2 < deg) ? __int_as_float(e2.y) : 0.f;
        float v3 = (j + 3 < deg) ? __int_as_float(e3.y) : 0.f;
        fma_h8(acc, v0, r0);
        fma_h8(acc, v1, r1);
        fma_h8(acc, v2, r2);
        fma_h8(acc, v3, r3);
    }
    if (out32) store_f8(out32, g, l, acc);
    if (out16) store_h8(out16, g, l, acc);
}

// Fused dual-operand SpMM: same CSR, same gather indices, two dense tables.
// Per edge gathers zA[col] and zB[col]; accumulates into accA / accB.
// Halves CSR traffic + loop overhead vs two passes; 8 x 16B loads in flight/lane.
__global__ __launch_bounds__(256) void spmm2_k(const int2* __restrict__ csr, const int* __restrict__ off,
                                               const int* __restrict__ cnt,
                                               const uint4* __restrict__ zA, const uint4* __restrict__ zB,
                                               float4* __restrict__ outA32, uint4* __restrict__ outA16,
                                               float4* __restrict__ outB32, uint4* __restrict__ outB16,
                                               int nrows) {
    int g = blockIdx.x * 32 + (threadIdx.x >> 3);
    int l = threadIdx.x & 7;
    if (g >= nrows) return;
    int start = off[g], deg = cnt[g];
    float accA[8], accB[8];
#pragma unroll
    for (int i = 0; i < 8; i++) { accA[i] = 0.f; accB[i] = 0.f; }
    for (int j = 0; j < deg; j += 4) {
        int j1 = min(j + 1, deg - 1);
        int j2 = min(j + 2, deg - 1);
        int j3 = min(j + 3, deg - 1);
        int2 e0 = csr[start + j];
        int2 e1 = csr[start + j1];
        int2 e2 = csr[start + j2];
        int2 e3 = csr[start + j3];
        int i0 = e0.x * 8 + l;
        int i1 = e1.x * 8 + l;
        int i2 = e2.x * 8 + l;
        int i3 = e3.x * 8 + l;
        uint4 a0 = zA[i0];
        uint4 a1 = zA[i1];
        uint4 a2 = zA[i2];
        uint4 a3 = zA[i3];
        uint4 b0 = zB[i0];
        uint4 b1 = zB[i1];
        uint4 b2 = zB[i2];
        uint4 b3 = zB[i3];
        float v0 = __int_as_float(e0.y);
        float v1 = (j + 1 < deg) ? __int_as_float(e1.y) : 0.f;
        float v2 = (j + 2 < deg) ? __int_as_float(e2.y) : 0.f;
        float v3 = (j + 3 < deg) ? __int_as_float(e3.y) : 0.f;
        fma_h8(accA, v0, a0);
        fma_h8(accA, v1, a1);
        fma_h8(accA, v2, a2);
        fma_h8(accA, v3, a3);
        fma_h8(accB, v0, b0);
        fma_h8(accB, v1, b1);
        fma_h8(accB, v2, b2);
        fma_h8(accB, v3, b3);
    }
    if (outA32) store_f8(outA32, g, l, accA);
    if (outA16) store_h8(outA16, g, l, accA);
    if (outB32) store_f8(outB32, g, l, accB);
    if (outB16) store_h8(outB16, g, l, accB);
}

// ---------------- dense projection: z16 = fp16(x @ W), D=64 ----------------
// block = 256 threads computes 256 rows x 64 cols; K-tile 32 staged in LDS
// (x transposed 32KB + W 8KB = 40KB -> 4 blocks/CU); 8x8 per-thread register tile.

template <int K>
__global__ __launch_bounds__(256) void gemm64_k(const float* __restrict__ x, const float* __restrict__ w,
                                                __half* __restrict__ z16, int nrows) {
    __shared__ float xs[32][256];  // [kk][row_local]
    __shared__ float wsh[32][64];  // [kk][col]
    int t = threadIdx.x;
    int tx = t & 7;    // col group: cols tx*8 .. tx*8+7
    int ty = t >> 3;   // row group: rows ty*8 .. ty*8+7
    int r0 = blockIdx.x * 256;

    float acc[8][8];
#pragma unroll
    for (int i = 0; i < 8; i++)
#pragma unroll
        for (int j = 0; j < 8; j++) acc[i][j] = 0.f;

    for (int k0 = 0; k0 < K; k0 += 32) {
        __syncthreads();  // previous tile fully consumed
        // stage x tile: this thread owns global row r0+t, k in [k0, k0+32)
        {
            int row = r0 + t;
            float4 f[8];
            if (row < nrows) {
                const float* xp = x + (size_t)row * K + k0;
#pragma unroll
                for (int q = 0; q < 8; q++) f[q] = *(const float4*)&xp[q * 4];
            } else {
#pragma unroll
                for (int q = 0; q < 8; q++) f[q] = make_float4(0.f, 0.f, 0.f, 0.f);
            }
#pragma unroll
            for (int q = 0; q < 8; q++) {
                xs[q * 4 + 0][t] = f[q].x;
                xs[q * 4 + 1][t] = f[q].y;
                xs[q * 4 + 2][t] = f[q].z;
                xs[q * 4 + 3][t] = f[q].w;
            }
            // stage W tile: 32x64 contiguous floats, 8 per thread
            const float* wp = w + (size_t)k0 * 64;
            float* wflat = &wsh[0][0];
            *(float4*)&wflat[t * 8 + 0] = *(const float4*)&wp[t * 8 + 0];
            *(float4*)&wflat[t * 8 + 4] = *(const float4*)&wp[t * 8 + 4];
        }
        __syncthreads();
#pragma unroll 8
        for (int kk = 0; kk < 32; kk++) {
            float a[8], b[8];
            *(float4*)&a[0] = *(float4*)&xs[kk][ty * 8 + 0];
            *(float4*)&a[4] = *(float4*)&xs[kk][ty * 8 + 4];
            *(float4*)&b[0] = *(float4*)&wsh[kk][tx * 8 + 0];
            *(float4*)&b[4] = *(float4*)&wsh[kk][tx * 8 + 4];
#pragma unroll
            for (int i = 0; i < 8; i++)
#pragma unroll
                for (int j = 0; j < 8; j++) acc[i][j] = fmaf(a[i], b[j], acc[i][j]);
        }
    }

    int row0 = r0 + ty * 8;
    if (row0 < nrows) {  // nrows % 8 == 0, so all 8 rows valid together
#pragma unroll
        for (int i = 0; i < 8; i++) {
            __half2 p0 = __floats2half2_rn(acc[i][0], acc[i][1]);
            __half2 p1 = __floats2half2_rn(acc[i][2], acc[i][3]);
            __half2 p2 = __floats2half2_rn(acc[i][4], acc[i][5]);
            __half2 p3 = __floats2half2_rn(acc[i][6], acc[i][7]);
            uint4 o;
            o.x = *(unsigned*)&p0;
            o.y = *(unsigned*)&p1;
            o.z = *(unsigned*)&p2;
            o.w = *(unsigned*)&p3;
            *(uint4*)&z16[(size_t)(row0 + i) * 64 + tx * 8] = o;
        }
    }
}

// ---------------- launch ----------------

extern "C" void kernel_launch(void* const* d_in, const int* in_sizes, int n_in,
                              void* d_out, int out_size, void* d_ws, size_t ws_size,
                              hipStream_t stream) {
    const float* x_paper  = (const float*)d_in[0];
    const float* x_author = (const float*)d_in[1];
    const float* W_paper  = (const float*)d_in[2];
    const float* W_author = (const float*)d_in[3];
    const int*   pa_row   = (const int*)d_in[4];
    const int*   pa_col   = (const int*)d_in[5];
    const float* pa_val   = (const float*)d_in[6];
    const int*   ap_row   = (const int*)d_in[7];
    const int*   ap_col   = (const int*)d_in[8];
    const float* ap_val   = (const float*)d_in[9];

    char* ws = (char*)d_ws;
    size_t o = 0;
    auto alloc = [&](size_t bytes) -> char* {
        char* p = ws + o;
        o += (bytes + 255) & ~(size_t)255;
        return p;
    };
    __half* zp16  = (__half*)alloc((size_t)NP * 64 * 2);  // zp, later reused as g
    __half* za16  = (__half*)alloc((size_t)NA * 64 * 2);
    __half* h16   = (__half*)alloc((size_t)NA * 64 * 2);  // h, later h2
    __half* pap16 = (__half*)alloc((size_t)NP * 64 * 2);
    int2*  csr_pa = (int2*)alloc((size_t)NE * 8);
    int2*  csr_ap = (int2*)alloc((size_t)NE * 8);
    int* cnt_pa = (int*)alloc(NA * 4);
    int* off_pa = (int*)alloc(NA * 4);
    int* cnt_ap = (int*)alloc(NP * 4);
    int* off_ap = (int*)alloc(NP * 4);
    int* cursor = (int*)alloc(NP * 4);
    int* bsums  = (int*)alloc(1024 * 4);

    float* out_pap   = (float*)d_out;
    float* out_papap = out_pap + (size_t)NP * 64;
    float* out_apa   = out_papap + (size_t)NP * 64;

    const int nb_a = (NA + 1023) / 1024;  // 98
    const int nb_p = (NP + 1023) / 1024;  // 196

    // CSR build: pa (rows = authors), ap (rows = papers)
    hipMemsetAsync(cnt_pa, 0, NA * 4, stream);
    hipMemsetAsync(cnt_ap, 0, NP * 4, stream);
    hist_k<<<1024, 256, 0, stream>>>(pa_row, cnt_pa, NE);
    hist_k<<<1024, 256, 0, stream>>>(ap_row, cnt_ap, NE);

    scan1_k<<<nb_a, 256, 0, stream>>>(cnt_pa, off_pa, bsums, NA);
    scan2_k<<<1, 256, 0, stream>>>(bsums, nb_a);
    scan3_k<<<nb_a, 256, 0, stream>>>(off_pa, bsums, NA);
    hipMemsetAsync(cursor, 0, NA * 4, stream);
    scatter_k<<<1024, 256, 0, stream>>>(pa_row, pa_col, pa_val, off_pa, cursor, csr_pa, NE);

    scan1_k<<<nb_p, 256, 0, stream>>>(cnt_ap, off_ap, bsums, NP);
    scan2_k<<<1, 256, 0, stream>>>(bsums, nb_p);
    scan3_k<<<nb_p, 256, 0, stream>>>(off_ap, bsums, NP);
    hipMemsetAsync(cursor, 0, NP * 4, stream);
    scatter_k<<<1024, 256, 0, stream>>>(ap_row, ap_col, ap_val, off_ap, cursor, csr_ap, NE);

    // projections (register-tiled GEMM, fp16 output)
    gemm64_k<256><<<(NP + 255) / 256, 256, 0, stream>>>(x_paper, W_paper, zp16, NP);
    gemm64_k<128><<<(NA + 255) / 256, 256, 0, stream>>>(x_author, W_author, za16, NA);

    // pass 1: h = pa@zp (fp16)
    spmm_k<<<NA / 32, 256, 0, stream>>>(csr_pa, off_pa, cnt_pa, (const uint4*)zp16,
                                        nullptr, (uint4*)h16, NA);
    // pass 2 (fused over csr_ap): pap = ap@h (fp32 out + fp16) ; g = ap@za (fp16, reuse zp16)
    spmm2_k<<<NP / 32, 256, 0, stream>>>(csr_ap, off_ap, cnt_ap,
                                         (const uint4*)h16, (const uint4*)za16,
                                         (float4*)out_pap, (uint4*)pap16,
                                         nullptr, (uint4*)zp16, NP);
    // pass 3 (fused over csr_pa): h2 = pa@pap (fp16, reuse h16) ; apa = pa@g (fp32 out)
    spmm2_k<<<NA / 32, 256, 0, stream>>>(csr_pa, off_pa, cnt_pa,
                                         (const uint4*)pap16, (const uint4*)zp16,
                                         nullptr, (uint4*)h16,
                                         (float4*)out_apa, nullptr, NA);
    // pass 4: papap = ap@h2 (fp32 out)
    spmm_k<<<NP / 32, 256, 0, stream>>>(csr_ap, off_ap, cnt_ap, (const uint4*)h16,
                                        (float4*)out_papap, nullptr, NP);
}